// Round 3
// baseline (195.476 us; speedup 1.0000x reference)
//
#include <hip/hip_runtime.h>
#include <math.h>

static constexpr int kC = 32, kR = 255, kE = 256;

// Static device scratch (graph-capture-safe).
__device__ float g_q0kv[768];            // [q0 | kc | vc] = W_{q,k,v}·cls + b
__device__ float g_qw[4 * 256];          // (q0_h^T W_k,h)*scale  [h][e]
__device__ float g_s0[4];                // score of key position 0 per head
__device__ float g_qb[4];                // (q0_h · b_k,h)*scale
__device__ float g_m[256 * 4 * 4];       // chunk max   [bc][chunk][h]
__device__ float g_l[256 * 4 * 4];       // chunk sum   [bc][chunk][h]
__device__ float g_part[256 * 4 * 4 * 256]; // partial xbar [bc][chunk][h][e]
__device__ float g_ln[256 * 256];        // LN output per token
__device__ float g_hact[256 * 1024];     // FFN hidden activations

// ---- Setup 1: rows of W_qkv · cls + b_qkv (768 dots), wave-per-row ----
__global__ __launch_bounds__(256) void k_setup1(const float* __restrict__ cls,
                                                const float* __restrict__ w_qkv,
                                                const float* __restrict__ b_qkv) {
  const int t = threadIdx.x, wv = t >> 6, l = t & 63;
  const int row = blockIdx.x * 4 + wv;  // 0..767
  float4 wv4 = *(const float4*)(w_qkv + (size_t)row * 256 + 4 * l);
  float4 cv4 = *(const float4*)(cls + 4 * l);
  float acc = wv4.x * cv4.x + wv4.y * cv4.y + wv4.z * cv4.z + wv4.w * cv4.w;
#pragma unroll
  for (int m = 1; m < 64; m <<= 1) acc += __shfl_xor(acc, m);
  if (l == 0) g_q0kv[row] = acc + b_qkv[row];
}

// ---- Setup 2: per-head qw row, s0, qb. One block per head. ----
__global__ __launch_bounds__(256) void k_setup2(const float* __restrict__ w_qkv,
                                                const float* __restrict__ b_qkv) {
  const int h = blockIdx.x, t = threadIdx.x;
  __shared__ float q0s[64];
  if (t < 64) q0s[t] = g_q0kv[h * 64 + t];
  __syncthreads();
  float acc = 0.f;
#pragma unroll 8
  for (int j = 0; j < 64; ++j)
    acc += q0s[j] * w_qkv[(size_t)(256 + h * 64 + j) * 256 + t];
  g_qw[h * 256 + t] = acc * 0.125f;
  if (t < 64) {
    float q = q0s[t];
    float pk = q * g_q0kv[256 + h * 64 + t];  // kc already includes b_k
    float pb = q * b_qkv[256 + h * 64 + t];
#pragma unroll
    for (int m = 1; m < 64; m <<= 1) {
      pk += __shfl_xor(pk, m);
      pb += __shfl_xor(pb, m);
    }
    if (t == 0) {
      g_s0[h] = pk * 0.125f;
      g_qb[h] = pb * 0.125f;
    }
  }
}

// ---- Attention chunks: scores + chunk softmax + partial weighted sums ----
__global__ __launch_bounds__(256) void k_attn(const float* __restrict__ x,
                                              const int* __restrict__ real_cols,
                                              const int* __restrict__ real_rows) {
  const int bc = blockIdx.x, chunk = blockIdx.y;
  const int b = bc >> 5, c = bc & 31;
  if (c >= real_cols[b]) return;
  const int rr = real_rows[b];
  const int r0 = chunk * 64;
  const int nr = min(64, rr - r0);
  if (nr <= 0) return;

  // Row-major x tile, row stride 260 floats (1040 B, 16B-aligned) so each
  // lane can stream its own row with ds_read_b128 at full bank utilization.
  __shared__ float xs[64][260];
  __shared__ float qws[4][256];
  __shared__ float ps[4][64];
  const int t = threadIdx.x, wv = t >> 6, l = t & 63;

#pragma unroll
  for (int i = 0; i < 4; ++i) qws[i][t] = g_qw[i * 256 + t];

  const float* xb = x + ((size_t)bc * kR + r0) * kE;
  for (int r = wv; r < nr; r += 4)
    *(float4*)&xs[r][4 * l] = *(const float4*)(xb + (size_t)r * kE + 4 * l);
  __syncthreads();

  // scores: thread = (row=l, head=wv); b128 LDS streams
  const int h = wv, row = l;
  float acc = 0.f;
  const float4* qrow = (const float4*)&qws[h][0];
  const float4* xrow = (const float4*)&xs[row][0];
#pragma unroll 8
  for (int e4 = 0; e4 < 64; ++e4) {
    float4 q4 = qrow[e4];
    float4 x4 = xrow[e4];
    acc += q4.x * x4.x + q4.y * x4.y + q4.z * x4.z + q4.w * x4.w;
  }
  float s = (row < nr) ? acc + g_qb[h] : -1e30f;
  float mx = s;
#pragma unroll
  for (int m = 1; m < 64; m <<= 1) mx = fmaxf(mx, __shfl_xor(mx, m));
  float p = (row < nr) ? __expf(s - mx) : 0.f;
  float lsum = p;
#pragma unroll
  for (int m = 1; m < 64; m <<= 1) lsum += __shfl_xor(lsum, m);
  ps[h][row] = p;
  if (l == 0) {
    g_m[(bc * 4 + chunk) * 4 + h] = mx;
    g_l[(bc * 4 + chunk) * 4 + h] = lsum;
  }
  __syncthreads();

  // partial weighted sums: thread t owns element e=t (stride-1 lanes, no conflict)
  float a0 = 0.f, a1 = 0.f, a2 = 0.f, a3 = 0.f;
  for (int r2 = 0; r2 < nr; ++r2) {
    float xv = xs[r2][t];
    a0 += ps[0][r2] * xv;
    a1 += ps[1][r2] * xv;
    a2 += ps[2][r2] * xv;
    a3 += ps[3][r2] * xv;
  }
  float* pp = g_part + (size_t)(bc * 4 + chunk) * 4 * 256;
  pp[0 * 256 + t] = a0;
  pp[1 * 256 + t] = a1;
  pp[2 * 256 + t] = a2;
  pp[3 * 256 + t] = a3;
}

// ---- Tail: merge chunks -> xbar -> ctx -> mha -> LN. 1 token/block ----
__global__ __launch_bounds__(256) void k_tail(const int* __restrict__ real_cols,
                                              const int* __restrict__ real_rows,
                                              const float* __restrict__ w_qkv,
                                              const float* __restrict__ w_out,
                                              const float* __restrict__ b_qkv,
                                              const float* __restrict__ b_out,
                                              const float* __restrict__ ln_g,
                                              const float* __restrict__ ln_b) {
  const int bc = blockIdx.x, b = bc >> 5, c = bc & 31;
  if (c >= real_cols[b]) return;  // g_ln stays stale; consumers are masked
  const int rr = real_rows[b];
  const int nch = (rr + 63) >> 6;
  const int t = threadIdx.x, wv = t >> 6, l = t & 63;

  __shared__ float xb[4][256];
  __shared__ float ctxs[256];
  __shared__ float al[4][4];  // [h][ch]
  __shared__ float p0s[4];
  __shared__ float rb[2][4];

  if (t < 4) {  // head h = t: flash-merge the chunk stats
    const int h = t;
    const float s0 = g_s0[h];
    float M = s0;
    for (int ch = 0; ch < nch; ++ch) M = fmaxf(M, g_m[(bc * 4 + ch) * 4 + h]);
    float lt = __expf(s0 - M);
    const float w0 = lt;
    float av[4] = {0.f, 0.f, 0.f, 0.f};
    for (int ch = 0; ch < nch; ++ch) {
      float e = __expf(g_m[(bc * 4 + ch) * 4 + h] - M);
      av[ch] = e;
      lt += g_l[(bc * 4 + ch) * 4 + h] * e;
    }
    const float inv = 1.f / lt;
#pragma unroll
    for (int ch = 0; ch < 4; ++ch) al[h][ch] = av[ch] * inv;
    p0s[h] = w0 * inv;
  }
  __syncthreads();

  // xbar[h][e=t]
#pragma unroll
  for (int h = 0; h < 4; ++h) {
    float a = 0.f;
    for (int ch = 0; ch < nch; ++ch)
      a += al[h][ch] * g_part[(size_t)(bc * 4 + ch) * 4 * 256 + h * 256 + t];
    xb[h][t] = a;
  }
  __syncthreads();

  // ctx[f=t]; h = wv (wave-uniform), xb reads broadcast
  {
    const int h = wv;
    const float p0 = p0s[h];
    const float* wrow = w_qkv + (size_t)(512 + t) * 256;
    float acc = p0 * g_q0kv[512 + t] + (1.f - p0) * b_qkv[512 + t];
    const float4* v4p = (const float4*)&xb[h][0];
#pragma unroll 8
    for (int e4 = 0; e4 < 64; ++e4) {
      float4 w4 = *(const float4*)(wrow + 4 * e4);
      float4 v4 = v4p[e4];
      acc += w4.x * v4.x + w4.y * v4.y + w4.z * v4.z + w4.w * v4.w;
    }
    ctxs[t] = acc;
  }
  __syncthreads();

  // mha[g=t]
  float mh;
  {
    const float* wrow = w_out + (size_t)t * 256;
    float acc = b_out[t];
    const float4* c4 = (const float4*)&ctxs[0];
#pragma unroll 8
    for (int e4 = 0; e4 < 64; ++e4) {
      float4 w4 = *(const float4*)(wrow + 4 * e4);
      float4 v4 = c4[e4];
      acc += w4.x * v4.x + w4.y * v4.y + w4.z * v4.z + w4.w * v4.w;
    }
    mh = acc;
  }

  // LayerNorm
  float s1 = mh, s2 = mh * mh;
#pragma unroll
  for (int m = 1; m < 64; m <<= 1) {
    s1 += __shfl_xor(s1, m);
    s2 += __shfl_xor(s2, m);
  }
  if (l == 0) {
    rb[0][wv] = s1;
    rb[1][wv] = s2;
  }
  __syncthreads();
  const float mu = (rb[0][0] + rb[0][1] + rb[0][2] + rb[0][3]) * (1.f / 256.f);
  const float msq = (rb[1][0] + rb[1][1] + rb[1][2] + rb[1][3]) * (1.f / 256.f);
  const float var = msq - mu * mu;
  g_ln[(size_t)bc * 256 + t] =
      (mh - mu) * rsqrtf(var + 1e-5f) * ln_g[t] + ln_b[t];
}

// ---- FFN1: h = relu(W1·ln + b1). Tile: 8 tokens x 128 features ----
__global__ __launch_bounds__(256) void k_ffn1(const float* __restrict__ w1,
                                              const float* __restrict__ b1,
                                              const int* __restrict__ real_cols) {
  const int tok0 = blockIdx.x * 8;
  const int b = tok0 >> 5, c0 = tok0 & 31;
  if (c0 >= real_cols[b]) return;  // whole 8-token group invalid
  __shared__ float lns[8][256];
  const int t = threadIdx.x;
  const int f0 = blockIdx.y * 128;
#pragma unroll
  for (int i = 0; i < 8; ++i) lns[i][t] = g_ln[(size_t)(tok0 + i) * 256 + t];
  __syncthreads();
  const int f = f0 + (t & 127), half = t >> 7;
  const float* wrow = w1 + (size_t)f * 256;
  const float bb = b1[f];
  float acc[4] = {bb, bb, bb, bb};
  for (int e = 0; e < 256; e += 4) {
    float4 w4 = *(const float4*)(wrow + e);
#pragma unroll
    for (int k = 0; k < 4; ++k) {
      const int i = half * 4 + k;
      acc[k] += w4.x * lns[i][e] + w4.y * lns[i][e + 1] +
                w4.z * lns[i][e + 2] + w4.w * lns[i][e + 3];
    }
  }
#pragma unroll
  for (int k = 0; k < 4; ++k)
    g_hact[(size_t)(tok0 + half * 4 + k) * 1024 + f] = fmaxf(acc[k], 0.f);
}

// ---- FFN2 + residual + column mask. Tile: 8 tokens x 32 outputs ----
__global__ __launch_bounds__(256) void k_ffn2(const float* __restrict__ w2,
                                              const float* __restrict__ b2,
                                              const int* __restrict__ real_cols,
                                              float* __restrict__ out) {
  const int t = threadIdx.x;
  const int tok0 = blockIdx.x * 8, e0 = blockIdx.y * 32;
  const int b = tok0 >> 5, c0 = tok0 & 31;
  const int ncols = real_cols[b];
  if (c0 >= ncols) {  // all 8 tokens invalid: just write the zero mask
    out[(size_t)(tok0 + (t >> 5)) * 256 + e0 + (t & 31)] = 0.f;
    return;
  }
  __shared__ float hs[8][1024];  // 32 KB
#pragma unroll
  for (int i = 0; i < 8; ++i) {
#pragma unroll
    for (int j = 0; j < 4; ++j)
      hs[i][j * 256 + t] = g_hact[(size_t)(tok0 + i) * 1024 + j * 256 + t];
  }
  __syncthreads();
  const int e = e0 + (t & 31), i = t >> 5;
  const int tok = tok0 + i, c = tok & 31;
  const float* wrow = w2 + (size_t)e * 1024;
  float acc = b2[e];
  for (int f = 0; f < 1024; f += 4) {
    float4 w4 = *(const float4*)(wrow + f);
    acc += w4.x * hs[i][f] + w4.y * hs[i][f + 1] + w4.z * hs[i][f + 2] +
           w4.w * hs[i][f + 3];
  }
  const float lnv = g_ln[(size_t)tok * 256 + e];
  out[(size_t)tok * 256 + e] = (c < ncols) ? (lnv + acc) : 0.f;
}

extern "C" void kernel_launch(void* const* d_in, const int* in_sizes, int n_in,
                              void* d_out, int out_size, void* d_ws, size_t ws_size,
                              hipStream_t stream) {
  const float* x = (const float*)d_in[0];
  const int* real_cols = (const int*)d_in[1];
  const int* real_rows = (const int*)d_in[2];
  const float* cls = (const float*)d_in[3];
  const float* w_qkv = (const float*)d_in[4];
  const float* b_qkv = (const float*)d_in[5];
  const float* w_out = (const float*)d_in[6];
  const float* b_out = (const float*)d_in[7];
  const float* ln_g = (const float*)d_in[8];
  const float* ln_b = (const float*)d_in[9];
  const float* w1 = (const float*)d_in[10];
  const float* b1 = (const float*)d_in[11];
  const float* w2 = (const float*)d_in[12];
  const float* b2 = (const float*)d_in[13];
  float* out = (float*)d_out;
  (void)in_sizes; (void)n_in; (void)out_size; (void)d_ws; (void)ws_size;

  k_setup1<<<192, 256, 0, stream>>>(cls, w_qkv, b_qkv);
  k_setup2<<<4, 256, 0, stream>>>(w_qkv, b_qkv);
  k_attn<<<dim3(256, 4), 256, 0, stream>>>(x, real_cols, real_rows);
  k_tail<<<256, 256, 0, stream>>>(real_cols, real_rows, w_qkv, w_out, b_qkv,
                                  b_out, ln_g, ln_b);
  k_ffn1<<<dim3(32, 8), 256, 0, stream>>>(w1, b1, real_cols);
  k_ffn2<<<dim3(32, 8), 256, 0, stream>>>(w2, b2, real_cols, out);
}

// Round 4
// 185.281 us; speedup vs baseline: 1.0550x; 1.0550x over previous
//
#include <hip/hip_runtime.h>
#include <hip/hip_bf16.h>
#include <math.h>

static constexpr int kC = 32, kR = 255, kE = 256;

// Static device scratch (graph-capture-safe).
__device__ float g_vc[256];              // W_v·cls + b_v
__device__ float g_qw[4 * 256];          // (q0_h^T W_k,h)*scale  [h][e]
__device__ float g_s0[4];                // score of key position 0 per head
__device__ float g_qb[4];                // (q0_h · b_k,h)*scale
__device__ float g_m[256 * 4 * 4];       // chunk max   [bc][chunk][h]
__device__ float g_l[256 * 4 * 4];       // chunk sum   [bc][chunk][h]
__device__ float g_part[256 * 4 * 4 * 256]; // partial xbar [bc][chunk][h][e]
__device__ float g_ln[256 * 256];        // LN output per token
__device__ float g_hact[256 * 1024];     // FFN hidden activations
// bf16 weight caches (recomputed every launch; halve tail/ffn L2 traffic)
__device__ unsigned short g_wv_bf[256 * 256];
__device__ unsigned short g_wout_bf[256 * 256];
__device__ unsigned short g_w1_bf[1024 * 256];
__device__ unsigned short g_w2_bf[256 * 1024];

__device__ inline unsigned short f2bf(float f) {
  __hip_bfloat16 h = __float2bfloat16(f);
  return __builtin_bit_cast(unsigned short, h);
}
__device__ inline float bflo(unsigned int u) { return __uint_as_float(u << 16); }
__device__ inline float bfhi(unsigned int u) { return __uint_as_float(u & 0xffff0000u); }

// ---- Fused setup: blocks 0..3 = per-head math (self-contained, redundant q0);
//      blocks 4..643 = fp32->bf16 weight casts. No inter-block dependencies. ----
__global__ __launch_bounds__(256) void k_setup(const float* __restrict__ cls,
                                               const float* __restrict__ w_qkv,
                                               const float* __restrict__ b_qkv,
                                               const float* __restrict__ w_out,
                                               const float* __restrict__ w1,
                                               const float* __restrict__ w2) {
  const int t = threadIdx.x;
  if (blockIdx.x >= 4) {  // cast blocks: 1024 elements each
    const int u = blockIdx.x - 4;  // 0..639
    const float* src;
    unsigned short* dst;
    size_t base;
    if (u < 64) { src = w_qkv + 512 * 256; dst = g_wv_bf; base = (size_t)u * 1024; }
    else if (u < 128) { src = w_out; dst = g_wout_bf; base = (size_t)(u - 64) * 1024; }
    else if (u < 384) { src = w1; dst = g_w1_bf; base = (size_t)(u - 128) * 1024; }
    else { src = w2; dst = g_w2_bf; base = (size_t)(u - 384) * 1024; }
    const size_t idx = base + (size_t)t * 4;
    float4 v = *(const float4*)(src + idx);
    ushort4 o;
    o.x = f2bf(v.x); o.y = f2bf(v.y); o.z = f2bf(v.z); o.w = f2bf(v.w);
    *(ushort4*)(dst + idx) = o;
    return;
  }

  const int h = blockIdx.x;  // head
  __shared__ float clss[256], q0s[256];
  clss[t] = cls[t];
  __syncthreads();
  // q0[t] = b_q[t] + W_q[t,:]·cls   (each head-block recomputes all 256)
  {
    float acc = b_qkv[t];
    const float4* wr = (const float4*)(w_qkv + (size_t)t * 256);
    const float4* c4 = (const float4*)clss;
#pragma unroll 8
    for (int e4 = 0; e4 < 64; ++e4) {
      float4 w4 = wr[e4], v4 = c4[e4];
      acc += w4.x * v4.x + w4.y * v4.y + w4.z * v4.z + w4.w * v4.w;
    }
    q0s[t] = acc;
  }
  __syncthreads();
  // qw[h][t] = scale * sum_j q0[h*64+j] * W_k[h*64+j, t]
  {
    float acc = 0.f;
#pragma unroll 8
    for (int j = 0; j < 64; ++j)
      acc += q0s[h * 64 + j] * w_qkv[(size_t)(256 + h * 64 + j) * 256 + t];
    g_qw[h * 256 + t] = acc * 0.125f;
  }
  if (t < 64) {  // wave 0: kc row-dots -> s0, qb
    const int row = 256 + h * 64 + t;
    float kc = b_qkv[row];
    const float4* wr = (const float4*)(w_qkv + (size_t)row * 256);
    const float4* c4 = (const float4*)clss;
#pragma unroll 8
    for (int e4 = 0; e4 < 64; ++e4) {
      float4 w4 = wr[e4], v4 = c4[e4];
      kc += w4.x * v4.x + w4.y * v4.y + w4.z * v4.z + w4.w * v4.w;
    }
    const float q = q0s[h * 64 + t];
    float pk = q * kc, pb = q * b_qkv[row];
#pragma unroll
    for (int m = 1; m < 64; m <<= 1) {
      pk += __shfl_xor(pk, m);
      pb += __shfl_xor(pb, m);
    }
    if (t == 0) {
      g_s0[h] = pk * 0.125f;
      g_qb[h] = pb * 0.125f;
    }
  } else if (t < 128) {  // wave 1: vc rows h*64 .. h*64+63
    const int f = h * 64 + (t - 64);
    const int row = 512 + f;
    float acc = b_qkv[row];
    const float4* wr = (const float4*)(w_qkv + (size_t)row * 256);
    const float4* c4 = (const float4*)clss;
#pragma unroll 8
    for (int e4 = 0; e4 < 64; ++e4) {
      float4 w4 = wr[e4], v4 = c4[e4];
      acc += w4.x * v4.x + w4.y * v4.y + w4.z * v4.z + w4.w * v4.w;
    }
    g_vc[f] = acc;
  }
}

// ---- Attention chunks: scores + chunk softmax + partial weighted sums ----
__global__ __launch_bounds__(256) void k_attn(const float* __restrict__ x,
                                              const int* __restrict__ real_cols,
                                              const int* __restrict__ real_rows) {
  const int bc = blockIdx.x, chunk = blockIdx.y;
  const int b = bc >> 5, c = bc & 31;
  if (c >= real_cols[b]) return;
  const int rr = real_rows[b];
  const int r0 = chunk * 64;
  const int nr = min(64, rr - r0);
  if (nr <= 0) return;

  __shared__ float xs[64][260];  // row stride 1040 B: 16B-aligned, uniform banks
  __shared__ float qws[4][256];
  __shared__ float ps[4][64];
  const int t = threadIdx.x, wv = t >> 6, l = t & 63;

#pragma unroll
  for (int i = 0; i < 4; ++i) qws[i][t] = g_qw[i * 256 + t];

  const float* xb = x + ((size_t)bc * kR + r0) * kE;
  for (int r = wv; r < nr; r += 4)
    *(float4*)&xs[r][4 * l] = *(const float4*)(xb + (size_t)r * kE + 4 * l);
  __syncthreads();

  // scores: thread = (row=l, head=wv); b128 LDS streams
  const int h = wv, row = l;
  float acc = 0.f;
  const float4* qrow = (const float4*)&qws[h][0];
  const float4* xrow = (const float4*)&xs[row][0];
#pragma unroll 8
  for (int e4 = 0; e4 < 64; ++e4) {
    float4 q4 = qrow[e4];
    float4 x4 = xrow[e4];
    acc += q4.x * x4.x + q4.y * x4.y + q4.z * x4.z + q4.w * x4.w;
  }
  float s = (row < nr) ? acc + g_qb[h] : -1e30f;
  float mx = s;
#pragma unroll
  for (int m = 1; m < 64; m <<= 1) mx = fmaxf(mx, __shfl_xor(mx, m));
  float p = (row < nr) ? __expf(s - mx) : 0.f;
  float lsum = p;
#pragma unroll
  for (int m = 1; m < 64; m <<= 1) lsum += __shfl_xor(lsum, m);
  ps[h][row] = p;
  if (l == 0) {
    g_m[(bc * 4 + chunk) * 4 + h] = mx;
    g_l[(bc * 4 + chunk) * 4 + h] = lsum;
  }
  __syncthreads();

  // partial weighted sums: thread t owns element e=t
  float a0 = 0.f, a1 = 0.f, a2 = 0.f, a3 = 0.f;
  for (int r2 = 0; r2 < nr; ++r2) {
    float xv = xs[r2][t];
    a0 += ps[0][r2] * xv;
    a1 += ps[1][r2] * xv;
    a2 += ps[2][r2] * xv;
    a3 += ps[3][r2] * xv;
  }
  float* pp = g_part + (size_t)(bc * 4 + chunk) * 4 * 256;
  pp[0 * 256 + t] = a0;
  pp[1 * 256 + t] = a1;
  pp[2 * 256 + t] = a2;
  pp[3 * 256 + t] = a3;
}

// ---- Tail: merge chunks -> xbar -> ctx -> mha -> LN (bf16 weights) ----
__global__ __launch_bounds__(256) void k_tail(const int* __restrict__ real_cols,
                                              const int* __restrict__ real_rows,
                                              const float* __restrict__ b_qkv,
                                              const float* __restrict__ b_out,
                                              const float* __restrict__ ln_g,
                                              const float* __restrict__ ln_b) {
  const int bc = blockIdx.x, b = bc >> 5, c = bc & 31;
  if (c >= real_cols[b]) return;  // g_ln stays stale; consumers are masked
  const int rr = real_rows[b];
  const int nch = (rr + 63) >> 6;
  const int t = threadIdx.x, wv = t >> 6, l = t & 63;

  __shared__ float xb[4][256];
  __shared__ float ctxs[256];
  __shared__ float al[4][4];  // [h][ch]
  __shared__ float p0s[4];
  __shared__ float rb[2][4];

  if (t < 4) {  // head h = t: flash-merge the chunk stats
    const int h = t;
    const float s0 = g_s0[h];
    float M = s0;
    for (int ch = 0; ch < nch; ++ch) M = fmaxf(M, g_m[(bc * 4 + ch) * 4 + h]);
    float lt = __expf(s0 - M);
    const float w0 = lt;
    float av[4] = {0.f, 0.f, 0.f, 0.f};
    for (int ch = 0; ch < nch; ++ch) {
      float e = __expf(g_m[(bc * 4 + ch) * 4 + h] - M);
      av[ch] = e;
      lt += g_l[(bc * 4 + ch) * 4 + h] * e;
    }
    const float inv = 1.f / lt;
#pragma unroll
    for (int ch = 0; ch < 4; ++ch) al[h][ch] = av[ch] * inv;
    p0s[h] = w0 * inv;
  }
  __syncthreads();

  // xbar[h][e=t]
#pragma unroll
  for (int h = 0; h < 4; ++h) {
    float a = 0.f;
    for (int ch = 0; ch < nch; ++ch)
      a += al[h][ch] * g_part[(size_t)(bc * 4 + ch) * 4 * 256 + h * 256 + t];
    xb[h][t] = a;
  }
  __syncthreads();

  // ctx[f=t]; h = wv (wave-uniform), bf16 W_v row stream
  {
    const int h = wv;
    const float p0 = p0s[h];
    float acc = p0 * g_vc[t] + (1.f - p0) * b_qkv[512 + t];
    const uint4* wr = (const uint4*)(g_wv_bf + (size_t)t * 256);
    const float4* v4p = (const float4*)&xb[h][0];
#pragma unroll 4
    for (int e8 = 0; e8 < 32; ++e8) {
      uint4 w = wr[e8];
      float4 a = v4p[2 * e8], bb = v4p[2 * e8 + 1];
      acc += bflo(w.x) * a.x + bfhi(w.x) * a.y + bflo(w.y) * a.z + bfhi(w.y) * a.w +
             bflo(w.z) * bb.x + bfhi(w.z) * bb.y + bflo(w.w) * bb.z + bfhi(w.w) * bb.w;
    }
    ctxs[t] = acc;
  }
  __syncthreads();

  // mha[g=t], bf16 W_out row stream
  float mh;
  {
    float acc = b_out[t];
    const uint4* wr = (const uint4*)(g_wout_bf + (size_t)t * 256);
    const float4* c4 = (const float4*)&ctxs[0];
#pragma unroll 4
    for (int e8 = 0; e8 < 32; ++e8) {
      uint4 w = wr[e8];
      float4 a = c4[2 * e8], bb = c4[2 * e8 + 1];
      acc += bflo(w.x) * a.x + bfhi(w.x) * a.y + bflo(w.y) * a.z + bfhi(w.y) * a.w +
             bflo(w.z) * bb.x + bfhi(w.z) * bb.y + bflo(w.w) * bb.z + bfhi(w.w) * bb.w;
    }
    mh = acc;
  }

  // LayerNorm
  float s1 = mh, s2 = mh * mh;
#pragma unroll
  for (int m = 1; m < 64; m <<= 1) {
    s1 += __shfl_xor(s1, m);
    s2 += __shfl_xor(s2, m);
  }
  if (l == 0) {
    rb[0][wv] = s1;
    rb[1][wv] = s2;
  }
  __syncthreads();
  const float mu = (rb[0][0] + rb[0][1] + rb[0][2] + rb[0][3]) * (1.f / 256.f);
  const float msq = (rb[1][0] + rb[1][1] + rb[1][2] + rb[1][3]) * (1.f / 256.f);
  const float var = msq - mu * mu;
  g_ln[(size_t)bc * 256 + t] =
      (mh - mu) * rsqrtf(var + 1e-5f) * ln_g[t] + ln_b[t];
}

// ---- FFN1: h = relu(W1·ln + b1), bf16 W1. Tile: 8 tokens x 128 features ----
__global__ __launch_bounds__(256) void k_ffn1(const float* __restrict__ b1,
                                              const int* __restrict__ real_cols) {
  const int tok0 = blockIdx.x * 8;
  const int b = tok0 >> 5, c0 = tok0 & 31;
  if (c0 >= real_cols[b]) return;
  __shared__ float lns[8][256];
  const int t = threadIdx.x;
  const int f0 = blockIdx.y * 128;
#pragma unroll
  for (int i = 0; i < 8; ++i) lns[i][t] = g_ln[(size_t)(tok0 + i) * 256 + t];
  __syncthreads();
  const int f = f0 + (t & 127), half = t >> 7;
  const uint4* wr = (const uint4*)(g_w1_bf + (size_t)f * 256);
  const float bb = b1[f];
  float acc[4] = {bb, bb, bb, bb};
  for (int e8 = 0; e8 < 32; ++e8) {
    uint4 w = wr[e8];
    const float wv0 = bflo(w.x), wv1 = bfhi(w.x), wv2 = bflo(w.y), wv3 = bfhi(w.y);
    const float wv4 = bflo(w.z), wv5 = bfhi(w.z), wv6 = bflo(w.w), wv7 = bfhi(w.w);
#pragma unroll
    for (int k = 0; k < 4; ++k) {
      const int i = half * 4 + k;
      const float4 a = *(const float4*)&lns[i][8 * e8];
      const float4 bbv = *(const float4*)&lns[i][8 * e8 + 4];
      acc[k] += wv0 * a.x + wv1 * a.y + wv2 * a.z + wv3 * a.w +
                wv4 * bbv.x + wv5 * bbv.y + wv6 * bbv.z + wv7 * bbv.w;
    }
  }
#pragma unroll
  for (int k = 0; k < 4; ++k)
    g_hact[(size_t)(tok0 + half * 4 + k) * 1024 + f] = fmaxf(acc[k], 0.f);
}

// ---- FFN2 + residual + column mask, bf16 W2. Tile: 8 tokens x 32 outputs ----
__global__ __launch_bounds__(256) void k_ffn2(const float* __restrict__ b2,
                                              const int* __restrict__ real_cols,
                                              float* __restrict__ out) {
  const int t = threadIdx.x;
  const int tok0 = blockIdx.x * 8, e0 = blockIdx.y * 32;
  const int b = tok0 >> 5, c0 = tok0 & 31;
  const int ncols = real_cols[b];
  if (c0 >= ncols) {  // all 8 tokens invalid: just write the zero mask
    out[(size_t)(tok0 + (t >> 5)) * 256 + e0 + (t & 31)] = 0.f;
    return;
  }
  __shared__ float hs[8][1024];  // 32 KB
#pragma unroll
  for (int i = 0; i < 8; ++i) {
#pragma unroll
    for (int j = 0; j < 4; ++j)
      hs[i][j * 256 + t] = g_hact[(size_t)(tok0 + i) * 1024 + j * 256 + t];
  }
  __syncthreads();
  const int e = e0 + (t & 31), i = t >> 5;
  const int tok = tok0 + i, c = tok & 31;
  const uint4* wr = (const uint4*)(g_w2_bf + (size_t)e * 1024);
  const float4* h4 = (const float4*)&hs[i][0];
  float acc = b2[e];
  for (int f8 = 0; f8 < 128; ++f8) {
    uint4 w = wr[f8];
    float4 a = h4[2 * f8], bb = h4[2 * f8 + 1];
    acc += bflo(w.x) * a.x + bfhi(w.x) * a.y + bflo(w.y) * a.z + bfhi(w.y) * a.w +
           bflo(w.z) * bb.x + bfhi(w.z) * bb.y + bflo(w.w) * bb.z + bfhi(w.w) * bb.w;
  }
  const float lnv = g_ln[(size_t)tok * 256 + e];
  out[(size_t)tok * 256 + e] = (c < ncols) ? (lnv + acc) : 0.f;
}

extern "C" void kernel_launch(void* const* d_in, const int* in_sizes, int n_in,
                              void* d_out, int out_size, void* d_ws, size_t ws_size,
                              hipStream_t stream) {
  const float* x = (const float*)d_in[0];
  const int* real_cols = (const int*)d_in[1];
  const int* real_rows = (const int*)d_in[2];
  const float* cls = (const float*)d_in[3];
  const float* w_qkv = (const float*)d_in[4];
  const float* b_qkv = (const float*)d_in[5];
  const float* w_out = (const float*)d_in[6];
  const float* b_out = (const float*)d_in[7];
  const float* ln_g = (const float*)d_in[8];
  const float* ln_b = (const float*)d_in[9];
  const float* w1 = (const float*)d_in[10];
  const float* b1 = (const float*)d_in[11];
  const float* w2 = (const float*)d_in[12];
  const float* b2 = (const float*)d_in[13];
  float* out = (float*)d_out;
  (void)in_sizes; (void)n_in; (void)out_size; (void)d_ws; (void)ws_size;

  k_setup<<<644, 256, 0, stream>>>(cls, w_qkv, b_qkv, w_out, w1, w2);
  k_attn<<<dim3(256, 4), 256, 0, stream>>>(x, real_cols, real_rows);
  k_tail<<<256, 256, 0, stream>>>(real_cols, real_rows, b_qkv, b_out, ln_g, ln_b);
  k_ffn1<<<dim3(32, 8), 256, 0, stream>>>(b1, real_cols);
  k_ffn2<<<dim3(32, 8), 256, 0, stream>>>(b2, real_cols, out);
}